// Round 1
// baseline (1281.305 us; speedup 1.0000x reference)
//
#include <hip/hip_runtime.h>

#define NN 100000
#define EE 1600000
#define DIN 512
#define DH 256
#define DOUT 32

typedef _Float16 h16x8 __attribute__((ext_vector_type(8)));
typedef _Float16 h16x4 __attribute__((ext_vector_type(4)));
typedef float f32x4 __attribute__((ext_vector_type(4)));

// ---------- weight transpose + fp16 convert ----------
__global__ __launch_bounds__(256) void conv_w1(const float* __restrict__ W1, _Float16* __restrict__ W1T){
  int i = blockIdx.x*256 + threadIdx.x;
  if (i < DIN*DH){
    int c = i >> 9, k = i & 511;          // W1T[c][k] = W1[k][c]
    W1T[i] = (_Float16)W1[k*DH + c];
  }
}
__global__ __launch_bounds__(256) void conv_w2(const float* __restrict__ W2, _Float16* __restrict__ W2T){
  int i = blockIdx.x*256 + threadIdx.x;
  if (i < DH*DOUT){
    int c = i >> 8, k = i & 255;          // W2T[c][k] = W2[k][c]
    W2T[i] = (_Float16)W2[k*DOUT + c];
  }
}

// ---------- GEMM1: h1 = feats @ W1 + b1  (fp16 MFMA, fp32 accum) ----------
__global__ __launch_bounds__(256) void gemm1(const float* __restrict__ feats,
    const _Float16* __restrict__ W1T, const float* __restrict__ b1,
    float* __restrict__ h1)
{
  __shared__ _Float16 At[128][40];   // pad 40 -> 80B row stride (16B-aligned)
  __shared__ _Float16 Bt[128][40];   // Bt[col][k] (transposed operand)
  const int tid = threadIdx.x;
  const int row0 = blockIdx.x * 128;
  const int col0 = blockIdx.y * 128;
  const int lane = tid & 63;
  const int wave = tid >> 6;
  const int wr = wave >> 1, wc = wave & 1;
  const int l15 = lane & 15, kg = lane >> 4;
  const int sRow = tid >> 1;
  const int sHalf = (tid & 1) * 16;

  f32x4 acc[4][4];
#pragma unroll
  for (int m=0;m<4;m++)
#pragma unroll
    for (int n=0;n<4;n++){ acc[m][n][0]=0.f; acc[m][n][1]=0.f; acc[m][n][2]=0.f; acc[m][n][3]=0.f; }

  const int gRow = row0 + sRow;
  const float* aP = feats + (size_t)gRow*DIN + sHalf;
  const _Float16* bP = W1T + (size_t)(col0 + sRow)*DIN + sHalf;

  for (int k0=0;k0<DIN;k0+=32){
    // stage A (fp32 -> fp16 fused)
    float4 f[4];
#pragma unroll
    for (int j=0;j<4;j++) f[j] = make_float4(0.f,0.f,0.f,0.f);
    if (gRow < NN){
      const float4* p = reinterpret_cast<const float4*>(aP + k0);
#pragma unroll
      for (int j=0;j<4;j++) f[j] = p[j];
    }
#pragma unroll
    for (int j=0;j<4;j++){
      h16x4 v;
      v[0]=(_Float16)f[j].x; v[1]=(_Float16)f[j].y; v[2]=(_Float16)f[j].z; v[3]=(_Float16)f[j].w;
      *reinterpret_cast<h16x4*>(&At[sRow][sHalf + j*4]) = v;
    }
    // stage B (already fp16, transposed layout)
    *reinterpret_cast<h16x8*>(&Bt[sRow][sHalf])   = *reinterpret_cast<const h16x8*>(bP + k0);
    *reinterpret_cast<h16x8*>(&Bt[sRow][sHalf+8]) = *reinterpret_cast<const h16x8*>(bP + k0 + 8);
    __syncthreads();

    h16x8 af[4], bfr[4];
#pragma unroll
    for (int m=0;m<4;m++) af[m]  = *reinterpret_cast<const h16x8*>(&At[wr*64 + m*16 + l15][kg*8]);
#pragma unroll
    for (int n=0;n<4;n++) bfr[n] = *reinterpret_cast<const h16x8*>(&Bt[wc*64 + n*16 + l15][kg*8]);
#pragma unroll
    for (int m=0;m<4;m++)
#pragma unroll
      for (int n=0;n<4;n++)
        acc[m][n] = __builtin_amdgcn_mfma_f32_16x16x32_f16(af[m], bfr[n], acc[m][n], 0, 0, 0);
    __syncthreads();
  }
  // epilogue: C row=(lane>>4)*4+j, col=lane&15 (verified gfx950 mapping)
  const int rb = kg*4;
#pragma unroll
  for (int n=0;n<4;n++){
    int col = col0 + wc*64 + n*16 + l15;
    float bias = b1[col];
#pragma unroll
    for (int m=0;m<4;m++){
#pragma unroll
      for (int j=0;j<4;j++){
        int g = row0 + wr*64 + m*16 + rb + j;
        if (g < NN) h1[(size_t)g*DH + col] = acc[m][n][j] + bias;
      }
    }
  }
}

// ---------- GEMM2: h0 = relu(h1) @ W2 + b2 ----------
__global__ __launch_bounds__(256) void gemm2(const float* __restrict__ h1,
    const _Float16* __restrict__ W2T, const float* __restrict__ b2,
    float* __restrict__ h0)
{
  __shared__ _Float16 At[256][40];
  __shared__ _Float16 Bt[32][264];   // full W2T, padded stride (264*2=528B, 16B-aligned, conflict-free)
  const int tid = threadIdx.x;
  const int row0 = blockIdx.x * 256;
  {
    int r = tid >> 3, c0 = (tid & 7) * 32;
    const h16x8* s = reinterpret_cast<const h16x8*>(W2T + r*DH + c0);
    h16x8* d = reinterpret_cast<h16x8*>(&Bt[r][c0]);
#pragma unroll
    for (int j=0;j<4;j++) d[j] = s[j];
  }
  const int lane = tid & 63, wave = tid >> 6;
  const int l15 = lane & 15, kg = lane >> 4;
  f32x4 acc[4][2];
#pragma unroll
  for (int m=0;m<4;m++)
#pragma unroll
    for (int n=0;n<2;n++){ acc[m][n][0]=0.f; acc[m][n][1]=0.f; acc[m][n][2]=0.f; acc[m][n][3]=0.f; }
  const int g = row0 + tid;
  for (int k0=0;k0<DH;k0+=32){
    float4 f[8];
#pragma unroll
    for (int j=0;j<8;j++) f[j]=make_float4(0.f,0.f,0.f,0.f);
    if (g < NN){
      const float4* p = reinterpret_cast<const float4*>(h1 + (size_t)g*DH + k0);
#pragma unroll
      for (int j=0;j<8;j++) f[j]=p[j];
    }
#pragma unroll
    for (int j=0;j<8;j++){
      h16x4 v;
      v[0]=(_Float16)fmaxf(f[j].x,0.f); v[1]=(_Float16)fmaxf(f[j].y,0.f);
      v[2]=(_Float16)fmaxf(f[j].z,0.f); v[3]=(_Float16)fmaxf(f[j].w,0.f);
      *reinterpret_cast<h16x4*>(&At[tid][j*4]) = v;
    }
    __syncthreads();
    h16x8 af[4], bfr[2];
#pragma unroll
    for (int m=0;m<4;m++) af[m]  = *reinterpret_cast<const h16x8*>(&At[wave*64 + m*16 + l15][kg*8]);
#pragma unroll
    for (int n=0;n<2;n++) bfr[n] = *reinterpret_cast<const h16x8*>(&Bt[n*16 + l15][k0 + kg*8]);
#pragma unroll
    for (int m=0;m<4;m++)
#pragma unroll
      for (int n=0;n<2;n++)
        acc[m][n] = __builtin_amdgcn_mfma_f32_16x16x32_f16(af[m], bfr[n], acc[m][n], 0,0,0);
    __syncthreads();
  }
  const int rb = kg*4;
#pragma unroll
  for (int n=0;n<2;n++){
    int col = n*16 + l15;
    float bias = b2[col];
#pragma unroll
    for (int m=0;m<4;m++){
#pragma unroll
      for (int j=0;j<4;j++){
        int gr = row0 + wave*64 + m*16 + rb + j;
        if (gr < NN) h0[(size_t)gr*DOUT + col] = acc[m][n][j] + bias;
      }
    }
  }
}

// ---------- graph prep ----------
__global__ __launch_bounds__(256) void deg_kernel(const int* __restrict__ src, const int* __restrict__ dst,
    int* __restrict__ degO, int* __restrict__ degI){
  int i = blockIdx.x*256 + threadIdx.x;
  if (i < EE){
    atomicAdd(&degO[src[i]], 1);
    atomicAdd(&degI[dst[i]], 1);
  }
}
__global__ __launch_bounds__(256) void norm_kernel(const int* __restrict__ degO, const int* __restrict__ degI,
    float* __restrict__ nS, float* __restrict__ nD){
  int i = blockIdx.x*256 + threadIdx.x;
  if (i < NN){
    int a = degO[i] > 0 ? degO[i] : 1;
    int b = degI[i] > 0 ? degI[i] : 1;
    nS[i] = 1.0f/sqrtf((float)a);
    nD[i] = 1.0f/sqrtf((float)b);
  }
}
__global__ __launch_bounds__(1024) void scan1(const int* __restrict__ degI, int* __restrict__ offs, int* __restrict__ bsum){
  __shared__ int sm[1024];
  int t = threadIdx.x;
  int g = blockIdx.x*1024 + t;
  int v = (g < NN) ? degI[g] : 0;
  sm[t] = v; __syncthreads();
  for (int o=1;o<1024;o<<=1){
    int a = (t>=o)? sm[t-o] : 0;
    __syncthreads();
    sm[t] += a;
    __syncthreads();
  }
  if (g < NN) offs[g] = sm[t] - v;
  if (t == 1023) bsum[blockIdx.x] = sm[t];
}
__global__ __launch_bounds__(128) void scan2(const int* __restrict__ bsum, int* __restrict__ boff, int nb){
  __shared__ int sm[128];
  int t = threadIdx.x;
  int v = (t < nb)? bsum[t] : 0;
  sm[t] = v; __syncthreads();
  for (int o=1;o<128;o<<=1){
    int a = (t>=o)? sm[t-o] : 0;
    __syncthreads();
    sm[t] += a;
    __syncthreads();
  }
  if (t < nb) boff[t] = sm[t] - v;
}
__global__ __launch_bounds__(256) void scan3(int* __restrict__ offs, const int* __restrict__ boff){
  int i = blockIdx.x*256 + threadIdx.x;
  if (i < NN) offs[i] += boff[i >> 10];
}
__global__ __launch_bounds__(256) void scatter_kernel(const int* __restrict__ src, const int* __restrict__ dst,
    const int* __restrict__ offs, int* __restrict__ cursor,
    const float* __restrict__ nS, const float* __restrict__ nD,
    int* __restrict__ csrc, float* __restrict__ cw){
  int i = blockIdx.x*256 + threadIdx.x;
  if (i < EE){
    int d = dst[i], s = src[i];
    int pos = offs[d] + atomicAdd(&cursor[d], 1);
    csrc[pos] = s;
    cw[pos] = nS[s] * nD[d];
  }
}

// ---------- APPNP pull-model propagation ----------
__global__ __launch_bounds__(256) void prop_kernel(const float* __restrict__ hin, const float* __restrict__ h0,
    float* __restrict__ hout, const int* __restrict__ offs, const int* __restrict__ degI,
    const int* __restrict__ csrc, const float* __restrict__ cw){
  int v = blockIdx.x*8 + (threadIdx.x >> 5);
  if (v >= NN) return;
  int f = threadIdx.x & 31;
  int beg = offs[v], cnt = degI[v];
  float acc = 0.f;
  for (int i=0;i<cnt;i++){
    int s = csrc[beg+i];
    float w = cw[beg+i];
    acc += w * hin[(size_t)s*DOUT + f];
  }
  hout[(size_t)v*DOUT + f] = 0.9f*acc + 0.1f*h0[(size_t)v*DOUT + f];
}

extern "C" void kernel_launch(void* const* d_in, const int* in_sizes, int n_in,
                              void* d_out, int out_size, void* d_ws, size_t ws_size,
                              hipStream_t stream)
{
  const float* feats = (const float*)d_in[0];
  const int*   src   = (const int*)d_in[1];
  const int*   dst   = (const int*)d_in[2];
  const float* W1    = (const float*)d_in[3];
  const float* b1    = (const float*)d_in[4];
  const float* W2    = (const float*)d_in[5];
  const float* b2    = (const float*)d_in[6];
  float* out = (float*)d_out;

  char* ws = (char*)d_ws;
  size_t off = 0;
  auto alloc = [&](size_t bytes) -> void* {
    void* p = ws + off;
    off = (off + bytes + 255) & ~(size_t)255;
    return p;
  };
  _Float16* W1T = (_Float16*)alloc((size_t)DIN*DH*2);
  _Float16* W2T = (_Float16*)alloc((size_t)DH*DOUT*2);
  int*   degO   = (int*)  alloc((size_t)NN*4);
  int*   degI   = (int*)  alloc((size_t)NN*4);
  float* nS     = (float*)alloc((size_t)NN*4);
  float* nD     = (float*)alloc((size_t)NN*4);
  int*   offs   = (int*)  alloc((size_t)NN*4);
  int*   cursor = (int*)  alloc((size_t)NN*4);
  int*   bsum   = (int*)  alloc(512);
  int*   boff   = (int*)  alloc(512);
  int*   csrc   = (int*)  alloc((size_t)EE*4);
  float* cw     = (float*)alloc((size_t)EE*4);
  float* h0     = (float*)alloc((size_t)NN*DOUT*4);
  float* hA     = (float*)alloc((size_t)NN*DOUT*4);
  float* hB     = (float*)alloc((size_t)NN*DOUT*4);

  hipMemsetAsync(degO,   0, (size_t)NN*4, stream);
  hipMemsetAsync(degI,   0, (size_t)NN*4, stream);
  hipMemsetAsync(cursor, 0, (size_t)NN*4, stream);

  conv_w1<<<(DIN*DH+255)/256, 256, 0, stream>>>(W1, W1T);
  conv_w2<<<(DH*DOUT+255)/256, 256, 0, stream>>>(W2, W2T);

  gemm1<<<dim3((NN+127)/128, DH/128), 256, 0, stream>>>(feats, W1T, b1, out);
  gemm2<<<(NN+255)/256, 256, 0, stream>>>(out, W2T, b2, h0);

  deg_kernel<<<(EE+255)/256, 256, 0, stream>>>(src, dst, degO, degI);
  norm_kernel<<<(NN+255)/256, 256, 0, stream>>>(degO, degI, nS, nD);
  int nb = (NN+1023)/1024;
  scan1<<<nb, 1024, 0, stream>>>(degI, offs, bsum);
  scan2<<<1, 128, 0, stream>>>(bsum, boff, nb);
  scan3<<<(NN+255)/256, 256, 0, stream>>>(offs, boff);
  scatter_kernel<<<(EE+255)/256, 256, 0, stream>>>(src, dst, offs, cursor, nS, nD, csrc, cw);

  const float* cur = h0;
  float* outh = out + (size_t)NN*DH;
  for (int it=0; it<10; ++it){
    float* nxt = (it==9)? outh : ((it&1)? hB : hA);
    prop_kernel<<<(NN+7)/8, 256, 0, stream>>>(cur, h0, nxt, offs, degI, csrc, cw);
    cur = nxt;
  }
}

// Round 2
// 807.264 us; speedup vs baseline: 1.5872x; 1.5872x over previous
//
#include <hip/hip_runtime.h>

#define NN 100000
#define EE 1600000
#define DIN 512
#define DH 256
#define DOUT 32

typedef _Float16 h16x8 __attribute__((ext_vector_type(8)));
typedef _Float16 h16x4 __attribute__((ext_vector_type(4)));
typedef float f32x4 __attribute__((ext_vector_type(4)));

union HU { unsigned int u; _Float16 h[2]; };

// ---------- weight transpose + fp16 convert ----------
__global__ __launch_bounds__(256) void conv_w1(const float* __restrict__ W1, _Float16* __restrict__ W1T){
  int i = blockIdx.x*256 + threadIdx.x;
  if (i < DIN*DH){
    int c = i >> 9, k = i & 511;          // W1T[c][k] = W1[k][c]
    W1T[i] = (_Float16)W1[k*DH + c];
  }
}
__global__ __launch_bounds__(256) void conv_w2(const float* __restrict__ W2, _Float16* __restrict__ W2T){
  int i = blockIdx.x*256 + threadIdx.x;
  if (i < DH*DOUT){
    int c = i >> 8, k = i & 255;          // W2T[c][k] = W2[k][c]
    W2T[i] = (_Float16)W2[k*DOUT + c];
  }
}

// ---------- GEMM1: h1 = feats @ W1 + b1  (fp16 MFMA, fp32 accum, issue-early pipeline) ----------
__global__ __launch_bounds__(256) void gemm1(const float* __restrict__ feats,
    const _Float16* __restrict__ W1T, const float* __restrict__ b1,
    float* __restrict__ h1)
{
  __shared__ _Float16 At[128][40];
  __shared__ _Float16 Bt[128][40];
  const int tid = threadIdx.x;
  const int row0 = blockIdx.x * 128;
  const int col0 = blockIdx.y * 128;
  const int lane = tid & 63;
  const int wave = tid >> 6;
  const int wr = wave >> 1, wc = wave & 1;
  const int l15 = lane & 15, kg = lane >> 4;
  const int sRow = tid >> 1;
  const int sHalf = (tid & 1) * 16;

  f32x4 acc[4][4];
#pragma unroll
  for (int m=0;m<4;m++)
#pragma unroll
    for (int n=0;n<4;n++){ acc[m][n][0]=0.f; acc[m][n][1]=0.f; acc[m][n][2]=0.f; acc[m][n][3]=0.f; }

  const int gRow = row0 + sRow;
  const bool aok = (gRow < NN);
  const float* aP = feats + (size_t)gRow*DIN + sHalf;
  const _Float16* bP = W1T + (size_t)(col0 + sRow)*DIN + sHalf;

  float4 f[4];
  h16x8 bv[2];
#pragma unroll
  for (int j=0;j<4;j++) f[j] = make_float4(0.f,0.f,0.f,0.f);
  if (aok){
    const float4* p = reinterpret_cast<const float4*>(aP);
#pragma unroll
    for (int j=0;j<4;j++) f[j] = p[j];
  }
  bv[0] = *reinterpret_cast<const h16x8*>(bP);
  bv[1] = *reinterpret_cast<const h16x8*>(bP + 8);

  for (int k0=0;k0<DIN;k0+=32){
    // store staged regs to LDS (fp32 -> fp16 fused for A)
#pragma unroll
    for (int j=0;j<4;j++){
      h16x4 v;
      v[0]=(_Float16)f[j].x; v[1]=(_Float16)f[j].y; v[2]=(_Float16)f[j].z; v[3]=(_Float16)f[j].w;
      *reinterpret_cast<h16x4*>(&At[sRow][sHalf + j*4]) = v;
    }
    *reinterpret_cast<h16x8*>(&Bt[sRow][sHalf])   = bv[0];
    *reinterpret_cast<h16x8*>(&Bt[sRow][sHalf+8]) = bv[1];
    __syncthreads();

    // issue next K-step's global loads early (hide HBM latency under MFMA)
    if (k0 + 32 < DIN){
      if (aok){
        const float4* p = reinterpret_cast<const float4*>(aP + k0 + 32);
#pragma unroll
        for (int j=0;j<4;j++) f[j] = p[j];
      }
      bv[0] = *reinterpret_cast<const h16x8*>(bP + k0 + 32);
      bv[1] = *reinterpret_cast<const h16x8*>(bP + k0 + 40);
    }

    h16x8 af[4], bfr[4];
#pragma unroll
    for (int m=0;m<4;m++) af[m]  = *reinterpret_cast<const h16x8*>(&At[wr*64 + m*16 + l15][kg*8]);
#pragma unroll
    for (int n=0;n<4;n++) bfr[n] = *reinterpret_cast<const h16x8*>(&Bt[wc*64 + n*16 + l15][kg*8]);
#pragma unroll
    for (int m=0;m<4;m++)
#pragma unroll
      for (int n=0;n<4;n++)
        acc[m][n] = __builtin_amdgcn_mfma_f32_16x16x32_f16(af[m], bfr[n], acc[m][n], 0, 0, 0);
    __syncthreads();
  }
  const int rb = kg*4;
#pragma unroll
  for (int n=0;n<4;n++){
    int col = col0 + wc*64 + n*16 + l15;
    float bias = b1[col];
#pragma unroll
    for (int m=0;m<4;m++){
#pragma unroll
      for (int j=0;j<4;j++){
        int g = row0 + wr*64 + m*16 + rb + j;
        if (g < NN) h1[(size_t)g*DH + col] = acc[m][n][j] + bias;
      }
    }
  }
}

// ---------- GEMM2: h0 = relu(h1) @ W2 + b2  -> fp16 packed output ----------
__global__ __launch_bounds__(256) void gemm2(const float* __restrict__ h1,
    const _Float16* __restrict__ W2T, const float* __restrict__ b2,
    _Float16* __restrict__ h0h)
{
  __shared__ _Float16 At[256][40];
  __shared__ _Float16 Bt[32][264];
  const int tid = threadIdx.x;
  const int row0 = blockIdx.x * 256;
  {
    int r = tid >> 3, c0 = (tid & 7) * 32;
    const h16x8* s = reinterpret_cast<const h16x8*>(W2T + r*DH + c0);
    h16x8* d = reinterpret_cast<h16x8*>(&Bt[r][c0]);
#pragma unroll
    for (int j=0;j<4;j++) d[j] = s[j];
  }
  const int lane = tid & 63, wave = tid >> 6;
  const int l15 = lane & 15, kg = lane >> 4;
  f32x4 acc[4][2];
#pragma unroll
  for (int m=0;m<4;m++)
#pragma unroll
    for (int n=0;n<2;n++){ acc[m][n][0]=0.f; acc[m][n][1]=0.f; acc[m][n][2]=0.f; acc[m][n][3]=0.f; }
  const int g = row0 + tid;
  const bool aok = (g < NN);

  float4 f[8];
#pragma unroll
  for (int j=0;j<8;j++) f[j]=make_float4(0.f,0.f,0.f,0.f);
  if (aok){
    const float4* p = reinterpret_cast<const float4*>(h1 + (size_t)g*DH);
#pragma unroll
    for (int j=0;j<8;j++) f[j]=p[j];
  }

  for (int k0=0;k0<DH;k0+=32){
#pragma unroll
    for (int j=0;j<8;j++){
      h16x4 v;
      v[0]=(_Float16)fmaxf(f[j].x,0.f); v[1]=(_Float16)fmaxf(f[j].y,0.f);
      v[2]=(_Float16)fmaxf(f[j].z,0.f); v[3]=(_Float16)fmaxf(f[j].w,0.f);
      *reinterpret_cast<h16x4*>(&At[tid][j*4]) = v;
    }
    __syncthreads();
    if (aok && k0 + 32 < DH){
      const float4* p = reinterpret_cast<const float4*>(h1 + (size_t)g*DH + k0 + 32);
#pragma unroll
      for (int j=0;j<8;j++) f[j]=p[j];
    }
    h16x8 af[4], bfr[2];
#pragma unroll
    for (int m=0;m<4;m++) af[m]  = *reinterpret_cast<const h16x8*>(&At[wave*64 + m*16 + l15][kg*8]);
#pragma unroll
    for (int n=0;n<2;n++) bfr[n] = *reinterpret_cast<const h16x8*>(&Bt[n*16 + l15][k0 + kg*8]);
#pragma unroll
    for (int m=0;m<4;m++)
#pragma unroll
      for (int n=0;n<2;n++)
        acc[m][n] = __builtin_amdgcn_mfma_f32_16x16x32_f16(af[m], bfr[n], acc[m][n], 0,0,0);
    __syncthreads();
  }
  const int rb = kg*4;
#pragma unroll
  for (int n=0;n<2;n++){
    int col = n*16 + l15;
    float bias = b2[col];
#pragma unroll
    for (int m=0;m<4;m++){
#pragma unroll
      for (int j=0;j<4;j++){
        int gr = row0 + wave*64 + m*16 + rb + j;
        if (gr < NN) h0h[(size_t)gr*DOUT + col] = (_Float16)(acc[m][n][j] + bias);
      }
    }
  }
}

// ---------- graph prep ----------
__global__ __launch_bounds__(256) void deg_kernel(const int* __restrict__ src, const int* __restrict__ dst,
    int* __restrict__ degO, int* __restrict__ degI){
  int i = blockIdx.x*256 + threadIdx.x;
  if (i < EE){
    atomicAdd(&degO[src[i]], 1);
    atomicAdd(&degI[dst[i]], 1);
  }
}
__global__ __launch_bounds__(256) void norm_kernel(const int* __restrict__ degO, const int* __restrict__ degI,
    float* __restrict__ nS, float* __restrict__ nD){
  int i = blockIdx.x*256 + threadIdx.x;
  if (i < NN){
    int a = degO[i] > 0 ? degO[i] : 1;
    int b = degI[i] > 0 ? degI[i] : 1;
    nS[i] = 1.0f/sqrtf((float)a);
    nD[i] = 1.0f/sqrtf((float)b);
  }
}
__global__ __launch_bounds__(1024) void scan1(const int* __restrict__ degI, int* __restrict__ offs, int* __restrict__ bsum){
  __shared__ int sm[1024];
  int t = threadIdx.x;
  int g = blockIdx.x*1024 + t;
  int v = (g < NN) ? degI[g] : 0;
  sm[t] = v; __syncthreads();
  for (int o=1;o<1024;o<<=1){
    int a = (t>=o)? sm[t-o] : 0;
    __syncthreads();
    sm[t] += a;
    __syncthreads();
  }
  if (g < NN) offs[g] = sm[t] - v;
  if (t == 1023) bsum[blockIdx.x] = sm[t];
}
__global__ __launch_bounds__(128) void scan2(const int* __restrict__ bsum, int* __restrict__ boff, int nb){
  __shared__ int sm[128];
  int t = threadIdx.x;
  int v = (t < nb)? bsum[t] : 0;
  sm[t] = v; __syncthreads();
  for (int o=1;o<128;o<<=1){
    int a = (t>=o)? sm[t-o] : 0;
    __syncthreads();
    sm[t] += a;
    __syncthreads();
  }
  if (t < nb) boff[t] = sm[t] - v;
}
__global__ __launch_bounds__(256) void scan3(int* __restrict__ offs, const int* __restrict__ boff){
  int i = blockIdx.x*256 + threadIdx.x;
  if (i < NN) offs[i] += boff[i >> 10];
}
__global__ __launch_bounds__(256) void scatter_kernel(const int* __restrict__ src, const int* __restrict__ dst,
    const int* __restrict__ offs, int* __restrict__ cursor,
    const float* __restrict__ nS, const float* __restrict__ nD,
    int2* __restrict__ edges){
  int i = blockIdx.x*256 + threadIdx.x;
  if (i < EE){
    int d = dst[i], s = src[i];
    int pos = offs[d] + atomicAdd(&cursor[d], 1);
    float w = nS[s] * nD[d];
    edges[pos] = make_int2(s, __float_as_int(w));
  }
}

// ---------- APPNP pull-model propagation (fp16 rows, 4 edge-slots/wave) ----------
template<bool LAST>
__global__ __launch_bounds__(256) void prop16(const unsigned int* __restrict__ hin,
    const unsigned int* __restrict__ h0h, unsigned int* __restrict__ outh,
    float* __restrict__ outf,
    const int* __restrict__ offs, const int* __restrict__ degI,
    const int2* __restrict__ edges)
{
  int v = blockIdx.x*4 + (threadIdx.x >> 6);
  if (v >= NN) return;
  int lane = threadIdx.x & 63;
  int es = lane >> 4;         // edge slot 0..3
  int c  = lane & 15;         // feature pair index (features 2c, 2c+1)
  int beg = offs[v], cnt = degI[v];
  float ax = 0.f, ay = 0.f;

  int i = es;
  while (i + 4 < cnt){
    int2 e0 = edges[beg + i];
    int2 e1 = edges[beg + i + 4];
    unsigned int p0 = hin[e0.x*16 + c];
    unsigned int p1 = hin[e1.x*16 + c];
    float w0 = __int_as_float(e0.y);
    float w1 = __int_as_float(e1.y);
    HU u0; u0.u = p0;
    HU u1; u1.u = p1;
    ax += w0 * (float)u0.h[0] + w1 * (float)u1.h[0];
    ay += w0 * (float)u0.h[1] + w1 * (float)u1.h[1];
    i += 8;
  }
  if (i < cnt){
    int2 e0 = edges[beg + i];
    unsigned int p0 = hin[e0.x*16 + c];
    float w0 = __int_as_float(e0.y);
    HU u0; u0.u = p0;
    ax += w0 * (float)u0.h[0];
    ay += w0 * (float)u0.h[1];
  }

  ax += __shfl_xor(ax, 16); ay += __shfl_xor(ay, 16);
  ax += __shfl_xor(ax, 32); ay += __shfl_xor(ay, 32);

  if (es == 0){
    HU h0u; h0u.u = h0h[v*16 + c];
    float rx = 0.9f*ax + 0.1f*(float)h0u.h[0];
    float ry = 0.9f*ay + 0.1f*(float)h0u.h[1];
    if (LAST){
      reinterpret_cast<float2*>(outf)[v*16 + c] = make_float2(rx, ry);
    } else {
      HU o; o.h[0] = (_Float16)rx; o.h[1] = (_Float16)ry;
      outh[v*16 + c] = o.u;
    }
  }
}

extern "C" void kernel_launch(void* const* d_in, const int* in_sizes, int n_in,
                              void* d_out, int out_size, void* d_ws, size_t ws_size,
                              hipStream_t stream)
{
  const float* feats = (const float*)d_in[0];
  const int*   src   = (const int*)d_in[1];
  const int*   dst   = (const int*)d_in[2];
  const float* W1    = (const float*)d_in[3];
  const float* b1    = (const float*)d_in[4];
  const float* W2    = (const float*)d_in[5];
  const float* b2    = (const float*)d_in[6];
  float* out = (float*)d_out;

  char* ws = (char*)d_ws;
  size_t off = 0;
  auto alloc = [&](size_t bytes) -> void* {
    void* p = ws + off;
    off = (off + bytes + 255) & ~(size_t)255;
    return p;
  };
  _Float16* W1T = (_Float16*)alloc((size_t)DIN*DH*2);
  _Float16* W2T = (_Float16*)alloc((size_t)DH*DOUT*2);
  int*   degO   = (int*)  alloc((size_t)NN*4);
  int*   degI   = (int*)  alloc((size_t)NN*4);
  float* nS     = (float*)alloc((size_t)NN*4);
  float* nD     = (float*)alloc((size_t)NN*4);
  int*   offs   = (int*)  alloc((size_t)NN*4);
  int*   cursor = (int*)  alloc((size_t)NN*4);
  int*   bsum   = (int*)  alloc(512);
  int*   boff   = (int*)  alloc(512);
  int2*  edges  = (int2*) alloc((size_t)EE*8);
  unsigned int* h0h = (unsigned int*)alloc((size_t)NN*DOUT*2);
  unsigned int* hA  = (unsigned int*)alloc((size_t)NN*DOUT*2);
  unsigned int* hB  = (unsigned int*)alloc((size_t)NN*DOUT*2);

  hipMemsetAsync(degO,   0, (size_t)NN*4, stream);
  hipMemsetAsync(degI,   0, (size_t)NN*4, stream);
  hipMemsetAsync(cursor, 0, (size_t)NN*4, stream);

  conv_w1<<<(DIN*DH+255)/256, 256, 0, stream>>>(W1, W1T);
  conv_w2<<<(DH*DOUT+255)/256, 256, 0, stream>>>(W2, W2T);

  gemm1<<<dim3((NN+127)/128, DH/128), 256, 0, stream>>>(feats, W1T, b1, out);
  gemm2<<<(NN+255)/256, 256, 0, stream>>>(out, W2T, b2, (_Float16*)h0h);

  deg_kernel<<<(EE+255)/256, 256, 0, stream>>>(src, dst, degO, degI);
  norm_kernel<<<(NN+255)/256, 256, 0, stream>>>(degO, degI, nS, nD);
  int nb = (NN+1023)/1024;
  scan1<<<nb, 1024, 0, stream>>>(degI, offs, bsum);
  scan2<<<1, 128, 0, stream>>>(bsum, boff, nb);
  scan3<<<(NN+255)/256, 256, 0, stream>>>(offs, boff);
  scatter_kernel<<<(EE+255)/256, 256, 0, stream>>>(src, dst, offs, cursor, nS, nD, edges);

  const unsigned int* cur = h0h;
  float* outh_f = out + (size_t)NN*DH;
  int nbv = (NN + 3) / 4;
  for (int it=0; it<9; ++it){
    unsigned int* nxt = (it&1)? hB : hA;
    prop16<false><<<nbv, 256, 0, stream>>>(cur, h0h, nxt, nullptr, offs, degI, edges);
    cur = nxt;
  }
  prop16<true><<<nbv, 256, 0, stream>>>(cur, h0h, nullptr, outh_f, offs, degI, edges);
}